// Round 7
// baseline (678.612 us; speedup 1.0000x reference)
//
#include <hip/hip_runtime.h>

// Chamfer loss via 32x32x16 MFMA, LDS-staged B panels. N=4, P1=P2=8192, D=3, K=1.
// d2 = |x|^2+|y|^2-2x.y == sum_{k<16} A[i][k]*B[j][k], fp16 hi/lo splits
// (products exact, fp32 MFMA accumulate; split residual ~2^-22 dropped):
//   A row-style: [h0,h1,h2, l0,l1,l2, h0,h1 | h2, wh,wl, 1,1, l0,l1,l2]
//   B col-style: [-2h0..2, -2h0..2, -2l0,-2l1 | -2l2, 1,1, qh,ql, -2l0..2]
// Same-lane-map A/B loading => k-permutation invariant (validated rounds 1-5,
// absmax 0). C/D layout (HW-verified): col=lane&31, row=(r&3)+8*(r>>2)+4*(lane>>5).
//
// Round-6/7 structure (fix for rounds 4/5's per-wave VMEM streaming):
//   block = 4 waves, owns 512 rows x 1024-col segment of one (pass,b).
//   Stage the 32KB B panel into LDS ONCE via global_load_lds (16B, source
//   pre-swizzled so ds_read_b128 is bank-conflict-free), one barrier, then a
//   barrier-free sweep: per 64-col pair {2 ds_read_b128 -> 8 MFMA -> 64 min3}.
//   Wave = 128 rows (4 A-frags persistent, acc 4x16).
//   Epilogue: DPP min-reduce (row_ror 1/2/4/8 + bcast15, VALU-speed, no LDS
//   pipe) -> part[pass][b][seg][row]; masked cols staged from a 32B pattern
//   giving d2 = |x|^2 + 65504 (never wins).
// chamfer_reduce: min over 8 seg slots per direction, clamp, scale, sum.
// (Round 7 = round 6 with dppmin ctrl as a template parameter: the builtin
// requires a constant-integer dpp_ctrl.)

typedef _Float16 f16;
typedef _Float16 half8 __attribute__((ext_vector_type(8)));
typedef float f32x16 __attribute__((ext_vector_type(16)));

constexpr int N = 4;
constexpr int P = 8192;
constexpr int NSEG = 8;
constexpr int SEGC = P / NSEG;     // 1024 cols per block
constexpr float BIGV = 1e30f;

__global__ __launch_bounds__(256) void chamfer_prep(
    const float* __restrict__ pred, const float* __restrict__ targ,
    f16* __restrict__ rowP, f16* __restrict__ colP,
    f16* __restrict__ rowT, f16* __restrict__ colT,
    f16* __restrict__ maskb)
{
    const int idx = blockIdx.x * 256 + threadIdx.x;    // [0, N*P)
    const f16 one = (f16)1.0f;
    #pragma unroll
    for (int which = 0; which < 2; ++which) {
        const float* s = (which ? targ : pred) + (size_t)idx * 3;
        half8* rdst = (half8*)((which ? rowT : rowP) + (size_t)idx * 16);
        half8* cdst = (half8*)((which ? colT : colP) + (size_t)idx * 16);
        const float x0 = s[0], x1 = s[1], x2 = s[2];
        const float w = fmaf(x0, x0, fmaf(x1, x1, x2 * x2));
        const f16 h0 = (f16)x0, h1 = (f16)x1, h2 = (f16)x2;
        const f16 l0 = (f16)(x0 - (float)h0), l1 = (f16)(x1 - (float)h1), l2 = (f16)(x2 - (float)h2);
        const f16 wh = (f16)w, wl = (f16)(w - (float)wh);
        half8 r0 = {h0, h1, h2, l0, l1, l2, h0, h1};
        half8 r1 = {h2, wh, wl, one, one, l0, l1, l2};
        rdst[0] = r0; rdst[1] = r1;
        const f16 n0 = (f16)(-2.0f * (float)h0), n1 = (f16)(-2.0f * (float)h1), n2 = (f16)(-2.0f * (float)h2);
        const f16 u0 = (f16)(-2.0f * (float)l0), u1 = (f16)(-2.0f * (float)l1), u2 = (f16)(-2.0f * (float)l2);
        half8 c0v = {n0, n1, n2, n0, n1, n2, u0, u1};
        half8 c1v = {u2, one, one, wh, wl, u0, u1, u2};
        cdst[0] = c0v; cdst[1] = c1v;
    }
    if (blockIdx.x == 0 && threadIdx.x == 0) {
        half8 m0 = {0, 0, 0, 0, 0, 0, 0, 0};
        half8 m1 = {0, one, one, (f16)65504.0f, 0, 0, 0, 0};   // d2 = |x|^2+65504
        ((half8*)maskb)[0] = m0; ((half8*)maskb)[1] = m1;
    }
}

template <int CTRL>
__device__ __forceinline__ float dppmin(float v) {
    int t = __builtin_amdgcn_update_dpp(__float_as_int(v), __float_as_int(v),
                                        CTRL, 0xf, 0xf, false);
    return fminf(v, __int_as_float(t));
}

__global__ __launch_bounds__(256, 3) void chamfer_pass(
    const f16* __restrict__ rowP, const f16* __restrict__ colP,
    const f16* __restrict__ rowT, const f16* __restrict__ colT,
    const f16* __restrict__ maskb,
    const int* __restrict__ lens, float* __restrict__ part)
{
    // XCD-chunked bijective swizzle (1024 % 8 == 0): 16 blocks sharing a
    // (pass,b,seg) B panel are consecutive Lids -> same XCD's L2.
    const int H   = blockIdx.x;
    const int Lid = (H & 7) * 128 + (H >> 3);
    const int ru   = Lid & 15;                 // 512-row unit
    const int seg  = (Lid >> 4) & 7;
    const int b    = (Lid >> 7) & 3;
    const int pass = Lid >> 9;

    const int L    = lens[b];
    const int Lcol = pass ? P : L;
    const int c0   = seg * SEGC;
    const int tid  = threadIdx.x;
    const int w    = tid >> 6;
    const int lane = tid & 63;
    const int lc   = lane & 31;                // B col within frag / A row
    const int kh   = lane >> 5;                // k half
    const int swz  = (lc >> 2) & 1;            // LDS half-swap swizzle bit

    float* prow = part + (((size_t)pass * N + b) * NSEG + seg) * P + ru * 512;

    if (c0 >= Lcol) {                          // pass0 only: no valid cols here
        prow[tid] = BIGV; prow[tid + 256] = BIGV;
        return;
    }
    if (pass && ru * 512 >= L) return;         // padded target rows: never read

    const f16* ab = (pass ? rowT : rowP) + (size_t)b * (P * 16);
    const f16* bb = (pass ? colP : colT) + (size_t)b * (P * 16);

    // ---- stage 32KB B panel into LDS (source pre-swizzled: halves of cols
    // with (col>>2)&1 swapped, so ds_read_b128 below is bank-conflict-free)
    __shared__ __align__(16) f16 sB[SEGC * 16];
    #pragma unroll
    for (int r = 0; r < 8; ++r) {
        const int cl = r * 128 + (tid >> 1);            // col within segment
        const int hg = (tid & 1) ^ ((cl >> 2) & 1);     // global half to fetch
        const int col = c0 + cl;
        const f16* src = (col < Lcol) ? (bb + (size_t)col * 16 + hg * 8)
                                      : (maskb + hg * 8);
        __builtin_amdgcn_global_load_lds(
            (const __attribute__((address_space(1))) void*)src,
            (__attribute__((address_space(3))) void*)(&sB[r * 2048 + tid * 8]),
            16, 0, 0);
    }

    // persistent A fragments: wave rows = ru*512 + w*128 + f*32 + lc
    const int row0 = ru * 512 + w * 128;
    half8 afr[4];
    #pragma unroll
    for (int f = 0; f < 4; ++f)
        afr[f] = *(const half8*)(ab + (size_t)(row0 + f * 32 + lc) * 16 + kh * 8);

    float acc[4][16];
    #pragma unroll
    for (int f = 0; f < 4; ++f)
        #pragma unroll
        for (int r = 0; r < 16; ++r) acc[f][r] = BIGV;

    __syncthreads();                           // panel ready (drains vmcnt)

    // ---- barrier-free sweep: 16 pairs of 32-col frags
    const f32x16 zz = {0.f,0.f,0.f,0.f, 0.f,0.f,0.f,0.f,
                       0.f,0.f,0.f,0.f, 0.f,0.f,0.f,0.f};
    const int rdoff = lc * 16 + (kh ^ swz) * 8;      // per-lane LDS offset (f16)

    half8 nb0 = *(const half8*)&sB[rdoff];
    half8 nb1 = *(const half8*)&sB[512 + rdoff];
    #pragma unroll 4
    for (int j = 0; j < 16; ++j) {
        const half8 b0 = nb0, b1 = nb1;
        if (j < 15) {
            nb0 = *(const half8*)&sB[(j + 1) * 1024 + rdoff];
            nb1 = *(const half8*)&sB[(j + 1) * 1024 + 512 + rdoff];
        }
        #pragma unroll
        for (int f = 0; f < 4; ++f) {
            const f32x16 d0 = __builtin_amdgcn_mfma_f32_32x32x16_f16(afr[f], b0, zz, 0, 0, 0);
            const f32x16 d1 = __builtin_amdgcn_mfma_f32_32x32x16_f16(afr[f], b1, zz, 0, 0, 0);
            #pragma unroll
            for (int r = 0; r < 16; ++r)
                acc[f][r] = fminf(fminf(acc[f][r], d0[r]), d1[r]);   // v_min3
        }
    }

    // ---- epilogue: DPP min-reduce over the 32 col-lanes (VALU, no LDS pipe).
    // row_ror 1/2/4/8 reduce each 16-lane row; bcast15 folds row0 into row1:
    // lanes 16-31 (kh=0) and 48-63 (kh=1) then hold the full 32-lane min.
    const int hi16 = (lane >> 4) & 1;
    #pragma unroll
    for (int f = 0; f < 4; ++f) {
        #pragma unroll
        for (int r = 0; r < 16; ++r) {
            float v = acc[f][r];
            v = dppmin<0x121>(v);              // row_ror:1
            v = dppmin<0x122>(v);              // row_ror:2
            v = dppmin<0x124>(v);              // row_ror:4
            v = dppmin<0x128>(v);              // row_ror:8
            v = dppmin<0x142>(v);              // row_bcast:15
            if (hi16 && (lc & 15) == r)        // 2 lanes: kh=0 and kh=1 rows
                prow[w * 128 + f * 32 + (r & 3) + 8 * (r >> 2) + 4 * kh] = v;
        }
    }
}

__global__ __launch_bounds__(256) void chamfer_reduce(
    const float* __restrict__ part, const int* __restrict__ lens,
    float* __restrict__ out)
{
    const int item = blockIdx.x * 256 + threadIdx.x;   // 2*N*P = 65536
    const int dir = item >> 15;
    const int b   = (item >> 13) & (N - 1);
    const int p   = item & (P - 1);
    const int L   = lens[b];

    float c = 0.f;
    if (dir == 0) {        // pred->targ
        const float* base = part + ((size_t)b * NSEG) * P + p;
        float v = base[0];
        #pragma unroll
        for (int s = 1; s < NSEG; ++s) v = fminf(v, base[(size_t)s * P]);
        c = fmaxf(v, 0.f) * (1.0f / ((float)P * (float)N));
    } else if (p < L) {    // targ->pred
        const float* base = part + (((size_t)N + b) * NSEG) * P + p;
        float v = base[0];
        #pragma unroll
        for (int s = 1; s < NSEG; ++s) v = fminf(v, base[(size_t)s * P]);
        c = fmaxf(v, 0.f) / ((float)L * (float)N);
    }
    #pragma unroll
    for (int off = 32; off; off >>= 1) c += __shfl_down(c, off, 64);
    __shared__ float acc[4];
    if ((threadIdx.x & 63) == 0) acc[threadIdx.x >> 6] = c;
    __syncthreads();
    if (threadIdx.x == 0) atomicAdd(out, acc[0] + acc[1] + acc[2] + acc[3]);
}

extern "C" void kernel_launch(void* const* d_in, const int* in_sizes, int n_in,
                              void* d_out, int out_size, void* d_ws, size_t ws_size,
                              hipStream_t stream)
{
    const float* pred = (const float*)d_in[0];
    const float* targ = (const float*)d_in[1];
    const int*   lens = (const int*)d_in[2];
    float* out = (float*)d_out;
    char*  ws  = (char*)d_ws;

    // ws: rowP|colP|rowT|colT (1MB each) | part 2MB | maskbuf 32B
    const size_t packb = (size_t)N * P * 16 * sizeof(f16);
    f16*   rowP = (f16*)ws;
    f16*   colP = (f16*)(ws + packb);
    f16*   rowT = (f16*)(ws + 2 * packb);
    f16*   colT = (f16*)(ws + 3 * packb);
    float* part = (float*)(ws + 4 * packb);
    f16*   maskb = (f16*)(ws + 4 * packb + (size_t)2 * N * NSEG * P * sizeof(float));

    (void)hipMemsetAsync(out, 0, out_size * sizeof(float), stream);
    chamfer_prep<<<(N * P) / 256, 256, 0, stream>>>(pred, targ, rowP, colP, rowT, colT, maskb);
    chamfer_pass<<<2 * N * 16 * NSEG, 256, 0, stream>>>(rowP, colP, rowT, colT, maskb, lens, part);
    chamfer_reduce<<<(2 * N * P) / 256, 256, 0, stream>>>(part, lens, out);
}

// Round 8
// 126.380 us; speedup vs baseline: 5.3696x; 5.3696x over previous
//
#include <hip/hip_runtime.h>

// Chamfer loss via 32x32x16 MFMA, LDS-staged B panels. N=4, P1=P2=8192, D=3, K=1.
// d2 = |x|^2+|y|^2-2x.y == sum_{k<16} A[i][k]*B[j][k], fp16 hi/lo splits
// (products exact, fp32 MFMA accumulate; split residual ~2^-22 dropped):
//   A row-style: [h0,h1,h2, l0,l1,l2, h0,h1 | h2, wh,wl, 1,1, l0,l1,l2]
//   B col-style: [-2h0..2, -2h0..2, -2l0,-2l1 | -2l2, 1,1, qh,ql, -2l0..2]
// Same-lane-map A/B loading => k-permutation invariant. C/D layout
// (HW-verified): col=lane&31, row=(r&3)+8*(r>>2)+4*(lane>>5).
// ALL of the above verified end-to-end in round 7 (absmax 0.0).
//
// Round-8 = round-7 with the register-pressure fix (round 7 spilled acc to
// scratch: WRITE_SIZE 1.2GB, VGPR_Count 84, 660us):
//   - wave owns 64 rows (2 A-frags, acc[2][16] = 32 VGPRs; worst-case live
//     set ~125 regs even with full MFMA clustering)
//   - no min-waves launch_bounds constraint (let the allocator breathe)
//   block = 4 waves = 256 rows x 1024-col segment of one (pass,b).
//   Stage the 32KB B panel into LDS ONCE via global_load_lds (16B, source
//   pre-swizzled so ds_read_b128 is bank-conflict-free), one barrier, then a
//   barrier-free sweep: per 64-col pair {2 ds_read_b128 -> 4 MFMA -> 32 min3}.
//   Epilogue: DPP min-reduce (row_ror 1/2/4/8 + bcast15, VALU-only)
//   -> part[pass][b][seg][row]; masked cols use a 32B pattern giving
//   d2 = |x|^2 + 65504 (never wins).
// chamfer_reduce: min over 8 seg slots per direction, clamp, scale, sum.

typedef _Float16 f16;
typedef _Float16 half8 __attribute__((ext_vector_type(8)));
typedef float f32x16 __attribute__((ext_vector_type(16)));

constexpr int N = 4;
constexpr int P = 8192;
constexpr int NSEG = 8;
constexpr int SEGC = P / NSEG;     // 1024 cols per block
constexpr int BROWS = 256;         // rows per block (4 waves x 64)
constexpr int NRU = P / BROWS;     // 32 row units
constexpr float BIGV = 1e30f;

__global__ __launch_bounds__(256) void chamfer_prep(
    const float* __restrict__ pred, const float* __restrict__ targ,
    f16* __restrict__ rowP, f16* __restrict__ colP,
    f16* __restrict__ rowT, f16* __restrict__ colT,
    f16* __restrict__ maskb)
{
    const int idx = blockIdx.x * 256 + threadIdx.x;    // [0, N*P)
    const f16 one = (f16)1.0f;
    #pragma unroll
    for (int which = 0; which < 2; ++which) {
        const float* s = (which ? targ : pred) + (size_t)idx * 3;
        half8* rdst = (half8*)((which ? rowT : rowP) + (size_t)idx * 16);
        half8* cdst = (half8*)((which ? colT : colP) + (size_t)idx * 16);
        const float x0 = s[0], x1 = s[1], x2 = s[2];
        const float w = fmaf(x0, x0, fmaf(x1, x1, x2 * x2));
        const f16 h0 = (f16)x0, h1 = (f16)x1, h2 = (f16)x2;
        const f16 l0 = (f16)(x0 - (float)h0), l1 = (f16)(x1 - (float)h1), l2 = (f16)(x2 - (float)h2);
        const f16 wh = (f16)w, wl = (f16)(w - (float)wh);
        half8 r0 = {h0, h1, h2, l0, l1, l2, h0, h1};
        half8 r1 = {h2, wh, wl, one, one, l0, l1, l2};
        rdst[0] = r0; rdst[1] = r1;
        const f16 n0 = (f16)(-2.0f * (float)h0), n1 = (f16)(-2.0f * (float)h1), n2 = (f16)(-2.0f * (float)h2);
        const f16 u0 = (f16)(-2.0f * (float)l0), u1 = (f16)(-2.0f * (float)l1), u2 = (f16)(-2.0f * (float)l2);
        half8 c0v = {n0, n1, n2, n0, n1, n2, u0, u1};
        half8 c1v = {u2, one, one, wh, wl, u0, u1, u2};
        cdst[0] = c0v; cdst[1] = c1v;
    }
    if (blockIdx.x == 0 && threadIdx.x == 0) {
        half8 m0 = {0, 0, 0, 0, 0, 0, 0, 0};
        half8 m1 = {0, one, one, (f16)65504.0f, 0, 0, 0, 0};   // d2 = |x|^2+65504
        ((half8*)maskb)[0] = m0; ((half8*)maskb)[1] = m1;
    }
}

template <int CTRL>
__device__ __forceinline__ float dppmin(float v) {
    int t = __builtin_amdgcn_update_dpp(__float_as_int(v), __float_as_int(v),
                                        CTRL, 0xf, 0xf, false);
    return fminf(v, __int_as_float(t));
}

__global__ __launch_bounds__(256) void chamfer_pass(
    const f16* __restrict__ rowP, const f16* __restrict__ colP,
    const f16* __restrict__ rowT, const f16* __restrict__ colT,
    const f16* __restrict__ maskb,
    const int* __restrict__ lens, float* __restrict__ part)
{
    // XCD-chunked bijective swizzle (2048 % 8 == 0): the 32 blocks sharing a
    // (pass,b,seg) B panel are consecutive Lids -> same XCD's L2.
    const int H   = blockIdx.x;
    const int Lid = (H & 7) * 256 + (H >> 3);
    const int ru   = Lid & (NRU - 1);          // 256-row unit
    const int seg  = (Lid >> 5) & 7;
    const int b    = (Lid >> 8) & 3;
    const int pass = Lid >> 10;

    const int L    = lens[b];
    const int Lcol = pass ? P : L;
    const int c0   = seg * SEGC;
    const int tid  = threadIdx.x;
    const int w    = tid >> 6;
    const int lane = tid & 63;
    const int lc   = lane & 31;                // B col within frag / A row
    const int kh   = lane >> 5;                // k half
    const int swz  = (lc >> 2) & 1;            // LDS half-swap swizzle bit

    float* prow = part + (((size_t)pass * N + b) * NSEG + seg) * P + ru * BROWS;

    if (c0 >= Lcol) {                          // pass0 only: no valid cols here
        prow[tid] = BIGV;
        return;
    }
    if (pass && ru * BROWS >= L) return;       // padded target rows: never read

    const f16* ab = (pass ? rowT : rowP) + (size_t)b * (P * 16);
    const f16* bb = (pass ? colP : colT) + (size_t)b * (P * 16);

    // ---- stage 32KB B panel into LDS (source pre-swizzled: halves of cols
    // with (col>>2)&1 swapped, so ds_read_b128 below is bank-conflict-free)
    __shared__ __align__(16) f16 sB[SEGC * 16];
    #pragma unroll
    for (int r = 0; r < 8; ++r) {
        const int cl = r * 128 + (tid >> 1);            // col within segment
        const int hg = (tid & 1) ^ ((cl >> 2) & 1);     // global half to fetch
        const int col = c0 + cl;
        const f16* src = (col < Lcol) ? (bb + (size_t)col * 16 + hg * 8)
                                      : (maskb + hg * 8);
        __builtin_amdgcn_global_load_lds(
            (const __attribute__((address_space(1))) void*)src,
            (__attribute__((address_space(3))) void*)(&sB[r * 2048 + tid * 8]),
            16, 0, 0);
    }

    // persistent A fragments: wave rows = ru*256 + w*64 + f*32 + lc
    const int row0 = ru * BROWS + w * 64;
    half8 afr[2];
    #pragma unroll
    for (int f = 0; f < 2; ++f)
        afr[f] = *(const half8*)(ab + (size_t)(row0 + f * 32 + lc) * 16 + kh * 8);

    float acc[2][16];
    #pragma unroll
    for (int f = 0; f < 2; ++f)
        #pragma unroll
        for (int r = 0; r < 16; ++r) acc[f][r] = BIGV;

    __syncthreads();                           // panel ready (drains vmcnt)

    // ---- barrier-free sweep: 16 pairs of 32-col frags
    const int rdoff = lc * 16 + (kh ^ swz) * 8;      // per-lane LDS offset (f16)

    half8 nb0 = *(const half8*)&sB[rdoff];
    half8 nb1 = *(const half8*)&sB[512 + rdoff];
    #pragma unroll 4
    for (int j = 0; j < 16; ++j) {
        const half8 b0 = nb0, b1 = nb1;
        if (j < 15) {
            nb0 = *(const half8*)&sB[(j + 1) * 1024 + rdoff];
            nb1 = *(const half8*)&sB[(j + 1) * 1024 + 512 + rdoff];
        }
        #pragma unroll
        for (int f = 0; f < 2; ++f) {
            const f32x16 zz = {0.f,0.f,0.f,0.f, 0.f,0.f,0.f,0.f,
                               0.f,0.f,0.f,0.f, 0.f,0.f,0.f,0.f};
            const f32x16 d0 = __builtin_amdgcn_mfma_f32_32x32x16_f16(afr[f], b0, zz, 0, 0, 0);
            const f32x16 d1 = __builtin_amdgcn_mfma_f32_32x32x16_f16(afr[f], b1, zz, 0, 0, 0);
            #pragma unroll
            for (int r = 0; r < 16; ++r)
                acc[f][r] = fminf(fminf(acc[f][r], d0[r]), d1[r]);   // v_min3
        }
    }

    // ---- epilogue: DPP min-reduce over the 32 col-lanes (VALU, no LDS pipe).
    // row_ror 1/2/4/8 reduce each 16-lane row; bcast15 folds row0 into row1:
    // lanes 16-31 (kh=0) and 48-63 (kh=1) then hold the full 32-lane min.
    const int hi16 = (lane >> 4) & 1;
    #pragma unroll
    for (int f = 0; f < 2; ++f) {
        #pragma unroll
        for (int r = 0; r < 16; ++r) {
            float v = acc[f][r];
            v = dppmin<0x121>(v);              // row_ror:1
            v = dppmin<0x122>(v);              // row_ror:2
            v = dppmin<0x124>(v);              // row_ror:4
            v = dppmin<0x128>(v);              // row_ror:8
            v = dppmin<0x142>(v);              // row_bcast:15
            if (hi16 && (lc & 15) == r)        // 2 lanes: kh=0 and kh=1 rows
                prow[w * 64 + f * 32 + (r & 3) + 8 * (r >> 2) + 4 * kh] = v;
        }
    }
}

__global__ __launch_bounds__(256) void chamfer_reduce(
    const float* __restrict__ part, const int* __restrict__ lens,
    float* __restrict__ out)
{
    const int item = blockIdx.x * 256 + threadIdx.x;   // 2*N*P = 65536
    const int dir = item >> 15;
    const int b   = (item >> 13) & (N - 1);
    const int p   = item & (P - 1);
    const int L   = lens[b];

    float c = 0.f;
    if (dir == 0) {        // pred->targ
        const float* base = part + ((size_t)b * NSEG) * P + p;
        float v = base[0];
        #pragma unroll
        for (int s = 1; s < NSEG; ++s) v = fminf(v, base[(size_t)s * P]);
        c = fmaxf(v, 0.f) * (1.0f / ((float)P * (float)N));
    } else if (p < L) {    // targ->pred
        const float* base = part + (((size_t)N + b) * NSEG) * P + p;
        float v = base[0];
        #pragma unroll
        for (int s = 1; s < NSEG; ++s) v = fminf(v, base[(size_t)s * P]);
        c = fmaxf(v, 0.f) / ((float)L * (float)N);
    }
    #pragma unroll
    for (int off = 32; off; off >>= 1) c += __shfl_down(c, off, 64);
    __shared__ float acc[4];
    if ((threadIdx.x & 63) == 0) acc[threadIdx.x >> 6] = c;
    __syncthreads();
    if (threadIdx.x == 0) atomicAdd(out, acc[0] + acc[1] + acc[2] + acc[3]);
}

extern "C" void kernel_launch(void* const* d_in, const int* in_sizes, int n_in,
                              void* d_out, int out_size, void* d_ws, size_t ws_size,
                              hipStream_t stream)
{
    const float* pred = (const float*)d_in[0];
    const float* targ = (const float*)d_in[1];
    const int*   lens = (const int*)d_in[2];
    float* out = (float*)d_out;
    char*  ws  = (char*)d_ws;

    // ws: rowP|colP|rowT|colT (1MB each) | part 2MB | maskbuf 32B
    const size_t packb = (size_t)N * P * 16 * sizeof(f16);
    f16*   rowP = (f16*)ws;
    f16*   colP = (f16*)(ws + packb);
    f16*   rowT = (f16*)(ws + 2 * packb);
    f16*   colT = (f16*)(ws + 3 * packb);
    float* part = (float*)(ws + 4 * packb);
    f16*   maskb = (f16*)(ws + 4 * packb + (size_t)2 * N * NSEG * P * sizeof(float));

    (void)hipMemsetAsync(out, 0, out_size * sizeof(float), stream);
    chamfer_prep<<<(N * P) / 256, 256, 0, stream>>>(pred, targ, rowP, colP, rowT, colT, maskb);
    chamfer_pass<<<2 * N * NRU * NSEG, 256, 0, stream>>>(rowP, colP, rowT, colT, maskb, lens, part);
    chamfer_reduce<<<(2 * N * P) / 256, 256, 0, stream>>>(part, lens, out);
}